// Round 1
// baseline (293.700 us; speedup 1.0000x reference)
//
#include <hip/hip_runtime.h>
#include <math.h>

#define L_SEQ 512
#define NH 8
#define HD 64
#define DD 192   // augmented feature dim: [64 qr/k | 64 | 64]

// ---------------- Kernel 1: QKV GEMM (f32) ----------------
// x:[4096,512] @ W:[512,1536] ->
//   sect 0 (q): Qt[row][0:64] = (q + r_r_bias) * 0.125
//   sect 1 (k): Kt[row][0:64] = k
//   sect 2 (v): Vv[row][0:64] = v
// row = (b*NH + h)*L_SEQ + l
__global__ __launch_bounds__(256) void qkv_gemm(
    const float* __restrict__ x, const float* __restrict__ W,
    const float* __restrict__ rr,
    float* __restrict__ Qt, float* __restrict__ Kt, float* __restrict__ Vv) {
  __shared__ float As[16][132];  // [kk][m], 128 rows + pad
  __shared__ float Bs[16][68];   // [kk][n], 64 cols + pad
  const int t = threadIdx.x;
  const int tx = t & 15, ty = t >> 4;
  const int m0 = blockIdx.x * 128, n0 = blockIdx.y * 64;

  float acc[8][4];
#pragma unroll
  for (int i = 0; i < 8; ++i)
#pragma unroll
    for (int j = 0; j < 4; ++j) acc[i][j] = 0.f;

  for (int k0 = 0; k0 < 512; k0 += 16) {
    __syncthreads();
#pragma unroll
    for (int i = 0; i < 8; ++i)
      As[tx][ty + i * 16] = x[(size_t)(m0 + ty + i * 16) * 512 + k0 + tx];
#pragma unroll
    for (int i = 0; i < 4; ++i) {
      const int kk = (t >> 6) + i * 4;
      Bs[kk][t & 63] = W[(size_t)(k0 + kk) * 1536 + n0 + (t & 63)];
    }
    __syncthreads();
#pragma unroll
    for (int kk = 0; kk < 16; ++kk) {
      float4 a0 = *(const float4*)&As[kk][ty * 8];
      float4 a1 = *(const float4*)&As[kk][ty * 8 + 4];
      float4 b4 = *(const float4*)&Bs[kk][tx * 4];
      float av[8] = {a0.x, a0.y, a0.z, a0.w, a1.x, a1.y, a1.z, a1.w};
      float bv[4] = {b4.x, b4.y, b4.z, b4.w};
#pragma unroll
      for (int i = 0; i < 8; ++i)
#pragma unroll
        for (int j = 0; j < 4; ++j)
          acc[i][j] = fmaf(av[i], bv[j], acc[i][j]);
    }
  }

  const int sect = n0 >> 9;            // 0=q, 1=k, 2=v (tile never crosses)
  const int h = (n0 & 511) >> 6;       // head (tile never crosses a head)
#pragma unroll
  for (int i = 0; i < 8; ++i) {
    const int m = m0 + ty * 8 + i;
    const int bidx = m >> 9, l = m & 511;
    const size_t row = ((size_t)bidx * NH + h) * L_SEQ + l;
    if (sect == 0) {
      float4 v;
      v.x = (acc[i][0] + rr[h * 64 + tx * 4 + 0]) * 0.125f;
      v.y = (acc[i][1] + rr[h * 64 + tx * 4 + 1]) * 0.125f;
      v.z = (acc[i][2] + rr[h * 64 + tx * 4 + 2]) * 0.125f;
      v.w = (acc[i][3] + rr[h * 64 + tx * 4 + 3]) * 0.125f;
      *(float4*)&Qt[row * DD + tx * 4] = v;
    } else if (sect == 1) {
      float4 v = make_float4(acc[i][0], acc[i][1], acc[i][2], acc[i][3]);
      *(float4*)&Kt[row * DD + tx * 4] = v;
    } else {
      float4 v = make_float4(acc[i][0], acc[i][1], acc[i][2], acc[i][3]);
      *(float4*)&Vv[row * HD + tx * 4] = v;
    }
  }
}

// ---------------- Kernel 2: build augmented features ----------------
// One thread per (row, h) pair, h in [0,32).
// Qt dims 64..191 and Kt dims 64..191 filled; Q-side carries the 1/8 scale.
__global__ void build_feats(float* __restrict__ Qt, float* __restrict__ Kt,
                            const float* __restrict__ rr,
                            const float* __restrict__ rw) {
  const int idx = blockIdx.x * blockDim.x + threadIdx.x;  // [0, 32768*32)
  const int h = idx & 31;
  const int row = idx >> 5;          // (b*NH + hh)*L_SEQ + l
  const int l = row & 511;
  const int hh = (row >> 9) & 7;

  const float f = expf(-(float)h * 0.29710775393472f);  // ln(10000)/31
  const float a0 = (float)l * f;
  const float a1 = (float)(l + 1) * f;
  const float s0 = sinf(a0), c0 = cosf(a0);
  const float s1 = sinf(a1), c1 = cosf(a1);

  const size_t base = (size_t)row * DD;
  // q side: stored qr' = 0.125*(q+rr); need qw' = 0.125*(q+rw)
  const float qr_s = Qt[base + h];
  const float qr_c = Qt[base + 32 + h];
  const float qw_s = qr_s + 0.125f * (rw[hh * 64 + h] - rr[hh * 64 + h]);
  const float qw_c = qr_c + 0.125f * (rw[hh * 64 + 32 + h] - rr[hh * 64 + 32 + h]);
  Qt[base + 64 + h]  = qw_s * c0 + qw_c * s0;
  Qt[base + 96 + h]  = qw_c * c0 - qw_s * s0;
  Qt[base + 128 + h] = 0.125f * s1;
  Qt[base + 160 + h] = 0.125f * c1;

  const float k_s = Kt[base + h];
  const float k_c = Kt[base + 32 + h];
  Kt[base + 64 + h]  = s1;
  Kt[base + 96 + h]  = c1;
  Kt[base + 128 + h] = k_s * c0 + k_c * s0;
  Kt[base + 160 + h] = k_c * c0 - k_s * s0;
}

// ---------------- Kernel 3: fused flash attention ----------------
// grid (L/64, B*NH); block 256 = 16x16, thread tile 4 rows x 4 cols.
__global__ __launch_bounds__(256) void attn_kernel(
    const float* __restrict__ Qt, const float* __restrict__ Kt,
    const float* __restrict__ Vv, const int* __restrict__ mask,
    float* __restrict__ out) {
  __shared__ float Qs[64][68];  // QK phase: [dim][qrow]; PV phase: Pt [k][qrow]
  __shared__ float Ks[64][68];  // QK phase: [dim][kcol]; PV phase: Vs [k][d]
  const int t = threadIdx.x;
  const int tx = t & 15, ty = t >> 4;
  const int qt = blockIdx.x, bh = blockIdx.y;
  const int b = bh >> 3, h = bh & 7;
  const int q0 = qt * 64;
  const size_t qrow0 = (size_t)bh * L_SEQ + q0;

  float o[4][4];
  float mrun[4], lrun[4];
#pragma unroll
  for (int i = 0; i < 4; ++i) {
    mrun[i] = -3.0e38f; lrun[i] = 0.f;
#pragma unroll
    for (int j = 0; j < 4; ++j) o[i][j] = 0.f;
  }

  for (int kt = 0; kt < 8; ++kt) {
    const size_t krow0 = (size_t)bh * L_SEQ + kt * 64;
    float s[4][4];
#pragma unroll
    for (int i = 0; i < 4; ++i)
#pragma unroll
      for (int j = 0; j < 4; ++j) s[i][j] = 0.f;

    // ---- S = Q̃·K̃ over 3 chunks of 64 dims ----
    for (int c = 0; c < 3; ++c) {
      __syncthreads();
      {
        const int d4 = tx * 4;
#pragma unroll
        for (int i = 0; i < 4; ++i) {
          const int r = ty + i * 16;
          float4 gq = *(const float4*)&Qt[(qrow0 + r) * DD + c * 64 + d4];
          Qs[d4 + 0][r] = gq.x; Qs[d4 + 1][r] = gq.y;
          Qs[d4 + 2][r] = gq.z; Qs[d4 + 3][r] = gq.w;
          float4 gk = *(const float4*)&Kt[(krow0 + r) * DD + c * 64 + d4];
          Ks[d4 + 0][r] = gk.x; Ks[d4 + 1][r] = gk.y;
          Ks[d4 + 2][r] = gk.z; Ks[d4 + 3][r] = gk.w;
        }
      }
      __syncthreads();
#pragma unroll 8
      for (int kk = 0; kk < 64; ++kk) {
        float4 a4 = *(const float4*)&Qs[kk][ty * 4];
        float4 b4 = *(const float4*)&Ks[kk][tx * 4];
        float av[4] = {a4.x, a4.y, a4.z, a4.w};
        float bv[4] = {b4.x, b4.y, b4.z, b4.w};
#pragma unroll
        for (int i = 0; i < 4; ++i)
#pragma unroll
          for (int j = 0; j < 4; ++j)
            s[i][j] = fmaf(av[i], bv[j], s[i][j]);
      }
    }

    // ---- mask (key axis) ----
    {
      int4 mk = *(const int4*)&mask[b * L_SEQ + kt * 64 + tx * 4];
      int mkv[4] = {mk.x, mk.y, mk.z, mk.w};
#pragma unroll
      for (int j = 0; j < 4; ++j)
        if (mkv[j] == 0) {
#pragma unroll
          for (int i = 0; i < 4; ++i) s[i][j] = -3.0e38f;
        }
    }

    // ---- online softmax (scale 1/8 already folded into Q̃) ----
#pragma unroll
    for (int i = 0; i < 4; ++i) {
      float tmax = fmaxf(fmaxf(s[i][0], s[i][1]), fmaxf(s[i][2], s[i][3]));
#pragma unroll
      for (int off = 1; off < 16; off <<= 1)
        tmax = fmaxf(tmax, __shfl_xor(tmax, off));
      const float mnew = fmaxf(mrun[i], tmax);
      const float corr = __expf(mrun[i] - mnew);
      float tsum = 0.f;
#pragma unroll
      for (int j = 0; j < 4; ++j) {
        s[i][j] = __expf(s[i][j] - mnew);
        tsum += s[i][j];
      }
#pragma unroll
      for (int off = 1; off < 16; off <<= 1)
        tsum += __shfl_xor(tsum, off);
      lrun[i] = lrun[i] * corr + tsum;
      mrun[i] = mnew;
#pragma unroll
      for (int j = 0; j < 4; ++j) o[i][j] *= corr;
    }

    __syncthreads();
    // ---- stage P^T into Qs buffer, V into Ks buffer ----
#pragma unroll
    for (int i = 0; i < 4; ++i)
#pragma unroll
      for (int j = 0; j < 4; ++j)
        Qs[tx * 4 + j][ty * 4 + i] = s[i][j];
    {
      const int d4 = tx * 4;
#pragma unroll
      for (int i = 0; i < 4; ++i) {
        const int k = ty + i * 16;
        float4 gv = *(const float4*)&Vv[(krow0 + k) * HD + d4];
        *(float4*)&Ks[k][d4] = gv;
      }
    }
    __syncthreads();

    // ---- O += P·V ----
#pragma unroll 8
    for (int k = 0; k < 64; ++k) {
      float4 p4 = *(const float4*)&Qs[k][ty * 4];
      float4 v4 = *(const float4*)&Ks[k][tx * 4];
      float pv[4] = {p4.x, p4.y, p4.z, p4.w};
      float vv[4] = {v4.x, v4.y, v4.z, v4.w};
#pragma unroll
      for (int i = 0; i < 4; ++i)
#pragma unroll
        for (int j = 0; j < 4; ++j)
          o[i][j] = fmaf(pv[i], vv[j], o[i][j]);
    }
  }

  // ---- normalize + write out[b, l, h*64+d] ----
#pragma unroll
  for (int i = 0; i < 4; ++i) {
    const int l = q0 + ty * 4 + i;
    const float inv = 1.0f / lrun[i];
    float4 r4 = make_float4(o[i][0] * inv, o[i][1] * inv,
                            o[i][2] * inv, o[i][3] * inv);
    *(float4*)&out[((size_t)b * L_SEQ + l) * 512 + h * 64 + tx * 4] = r4;
  }
}

extern "C" void kernel_launch(void* const* d_in, const int* in_sizes, int n_in,
                              void* d_out, int out_size, void* d_ws, size_t ws_size,
                              hipStream_t stream) {
  const float* x    = (const float*)d_in[0];
  const int*   mask = (const int*)d_in[1];
  const float* W    = (const float*)d_in[2];
  const float* rr   = (const float*)d_in[3];
  const float* rw   = (const float*)d_in[4];
  float* out = (float*)d_out;

  // workspace: Qt [32768,192] f32 | Kt [32768,192] f32 | V [32768,64] f32 = 56 MB
  float* Qt = (float*)d_ws;
  float* Kt = Qt + (size_t)32768 * DD;
  float* Vv = Kt + (size_t)32768 * DD;

  qkv_gemm<<<dim3(32, 24), 256, 0, stream>>>(x, W, rr, Qt, Kt, Vv);
  build_feats<<<4096, 256, 0, stream>>>(Qt, Kt, rr, rw);
  attn_kernel<<<dim3(8, NH * 8), 256, 0, stream>>>(Qt, Kt, Vv, mask, out);
}

// Round 2
// 119.585 us; speedup vs baseline: 2.4560x; 2.4560x over previous
//
#include <hip/hip_runtime.h>
#include <math.h>

#define LSEQ 512
#define DDIM 192

typedef __attribute__((ext_vector_type(8))) short s16x8;
typedef __attribute__((ext_vector_type(4))) float f32x4;
typedef unsigned short ushort_t;
typedef unsigned int uint_t;

#define MFMA16(a, b, c) __builtin_amdgcn_mfma_f32_16x16x32_bf16(a, b, c, 0, 0, 0)

__device__ __forceinline__ ushort_t f2b(float f) {
  union { float f; uint_t u; } v; v.f = f;
  uint_t r = (v.u + 0x7FFFu + ((v.u >> 16) & 1u)) >> 16;
  return (ushort_t)r;
}
__device__ __forceinline__ float b2f(ushort_t u) {
  union { uint_t u; float f; } v; v.u = ((uint_t)u) << 16;
  return v.f;
}

// ---------------- cast x -> bf16 ----------------
__global__ void cast_x(const float* __restrict__ x, ushort_t* __restrict__ xb) {
  const int i = (blockIdx.x * 256 + threadIdx.x) * 8;
  float4 a = *(const float4*)(x + i);
  float4 b = *(const float4*)(x + i + 4);
  uint4 o;
  o.x = (uint_t)f2b(a.x) | ((uint_t)f2b(a.y) << 16);
  o.y = (uint_t)f2b(a.z) | ((uint_t)f2b(a.w) << 16);
  o.z = (uint_t)f2b(b.x) | ((uint_t)f2b(b.y) << 16);
  o.w = (uint_t)f2b(b.z) | ((uint_t)f2b(b.w) << 16);
  *(uint4*)(xb + i) = o;
}

// ---------------- cast+transpose W: Wt[n][k] = bf16(W[k][n]) ----------------
__global__ void cast_transpose_w(const float* __restrict__ W, ushort_t* __restrict__ Wt) {
  __shared__ float tile[32][33];
  const int tx = threadIdx.x & 31, ty = threadIdx.x >> 5;  // ty 0..7
  const int k0 = blockIdx.x * 32, n0 = blockIdx.y * 32;
#pragma unroll
  for (int i = 0; i < 4; ++i)
    tile[ty + i * 8][tx] = W[(size_t)(k0 + ty + i * 8) * 1536 + n0 + tx];
  __syncthreads();
#pragma unroll
  for (int i = 0; i < 4; ++i)
    Wt[(size_t)(n0 + ty + i * 8) * 512 + k0 + tx] = f2b(tile[tx][ty + i * 8]);
}

// ---------------- QKV GEMM: bf16 MFMA, 64x64 wave tiles ----------------
// M=4096 (b,l), N=1536 (sect,head,d), K=512.  1536 one-wave blocks.
__global__ __launch_bounds__(64, 2) void qkv_gemm(
    const ushort_t* __restrict__ xb, const ushort_t* __restrict__ Wt,
    const float* __restrict__ rr,
    ushort_t* __restrict__ Qt, ushort_t* __restrict__ Kt, ushort_t* __restrict__ Vt) {
  const int id = blockIdx.x;
  const int t = id >> 3;
  const int np = t % 24, mp = (id & 7) + 8 * (t / 24);  // same-mp panels -> same XCD
  const int m0 = mp * 64, n0 = np * 64;
  const int lane = threadIdx.x, lo = lane & 15, hi = lane >> 4;

  f32x4 acc[4][4];
  const f32x4 zero4 = {0.f, 0.f, 0.f, 0.f};
#pragma unroll
  for (int i = 0; i < 4; ++i)
#pragma unroll
    for (int j = 0; j < 4; ++j) acc[i][j] = zero4;

  const ushort_t* abase = xb + (size_t)(m0 + lo) * 512 + hi * 8;
  const ushort_t* bbase = Wt + (size_t)(n0 + lo) * 512 + hi * 8;

#pragma unroll 2
  for (int ks = 0; ks < 16; ++ks) {
    s16x8 af[4], bf[4];
#pragma unroll
    for (int i = 0; i < 4; ++i) af[i] = *(const s16x8*)(abase + (size_t)i * 16 * 512 + ks * 32);
#pragma unroll
    for (int j = 0; j < 4; ++j) bf[j] = *(const s16x8*)(bbase + (size_t)j * 16 * 512 + ks * 32);
#pragma unroll
    for (int i = 0; i < 4; ++i)
#pragma unroll
      for (int j = 0; j < 4; ++j)
        acc[i][j] = MFMA16(af[i], bf[j], acc[i][j]);
  }

  const int sect = n0 >> 9;
  const int h = (n0 >> 6) & 7;

  if (sect == 0) {
    float bias[4];
#pragma unroll
    for (int j = 0; j < 4; ++j) bias[j] = rr[h * 64 + j * 16 + lo];
#pragma unroll
    for (int i = 0; i < 4; ++i)
#pragma unroll
      for (int r = 0; r < 4; ++r) {
        const int m = m0 + i * 16 + hi * 4 + r;
        const size_t row = ((size_t)(m >> 9) * 8 + h) * 512 + (m & 511);
#pragma unroll
        for (int j = 0; j < 4; ++j)
          Qt[row * DDIM + j * 16 + lo] = f2b((acc[i][j][r] + bias[j]) * 0.125f);
      }
  } else if (sect == 1) {
#pragma unroll
    for (int i = 0; i < 4; ++i)
#pragma unroll
      for (int r = 0; r < 4; ++r) {
        const int m = m0 + i * 16 + hi * 4 + r;
        const size_t row = ((size_t)(m >> 9) * 8 + h) * 512 + (m & 511);
#pragma unroll
        for (int j = 0; j < 4; ++j)
          Kt[row * DDIM + j * 16 + lo] = f2b(acc[i][j][r]);
      }
  } else {
#pragma unroll
    for (int i = 0; i < 4; ++i)
#pragma unroll
      for (int r = 0; r < 4; ++r) {
        const int m = m0 + i * 16 + hi * 4 + r;
        const int b = m >> 9, l = m & 511;
#pragma unroll
        for (int j = 0; j < 4; ++j)
          Vt[(((size_t)b * 8 + h) * 64 + j * 16 + lo) * 512 + l] = f2b(acc[i][j][r]);
      }
  }
}

// ---------------- build augmented features (bf16) ----------------
__global__ void build_feats(ushort_t* __restrict__ Qt, ushort_t* __restrict__ Kt,
                            const float* __restrict__ rr, const float* __restrict__ rw) {
  const int idx = blockIdx.x * blockDim.x + threadIdx.x;
  const int h = idx & 31;
  const int row = idx >> 5;
  const int l = row & 511;
  const int hh = (row >> 9) & 7;

  const float f = __expf(-(float)h * 0.29710775393472f);  // ln(10000)/31
  const float a0 = (float)l * f;
  const float a1 = (float)(l + 1) * f;
  float s0, c0, s1, c1;
  __sincosf(a0, &s0, &c0);
  __sincosf(a1, &s1, &c1);

  const size_t base = (size_t)row * DDIM;
  const float qr_s = b2f(Qt[base + h]);
  const float qr_c = b2f(Qt[base + 32 + h]);
  const float qw_s = qr_s + 0.125f * (rw[hh * 64 + h] - rr[hh * 64 + h]);
  const float qw_c = qr_c + 0.125f * (rw[hh * 64 + 32 + h] - rr[hh * 64 + 32 + h]);
  Qt[base + 64 + h]  = f2b(qw_s * c0 + qw_c * s0);
  Qt[base + 96 + h]  = f2b(qw_c * c0 - qw_s * s0);
  Qt[base + 128 + h] = f2b(0.125f * s1);
  Qt[base + 160 + h] = f2b(0.125f * c1);

  const float k_s = b2f(Kt[base + h]);
  const float k_c = b2f(Kt[base + 32 + h]);
  Kt[base + 64 + h]  = f2b(s1);
  Kt[base + 96 + h]  = f2b(c1);
  Kt[base + 128 + h] = f2b(k_s * c0 + k_c * s0);
  Kt[base + 160 + h] = f2b(k_c * c0 - k_s * s0);
}

// ---------------- fused flash attention: 1 wave per 16 q-rows ----------------
// 2048 blocks x 64 threads. Direct-global K/V frags (L2-resident per head),
// XCD swizzle keeps same-head blocks on one XCD. No __syncthreads anywhere.
__global__ __launch_bounds__(64, 2) void attn_kernel(
    const ushort_t* __restrict__ Qt, const ushort_t* __restrict__ Kt,
    const ushort_t* __restrict__ Vt, const int* __restrict__ mask,
    float* __restrict__ out) {
  __shared__ ushort_t P[16][72];  // 144B stride: balanced banks, 16B aligned

  const int id = blockIdx.x;
  const int qt = (id >> 3) & 31;
  const int bh = (id & 7) + 8 * (id >> 8);  // blocks with same bh -> same XCD
  const int b = bh >> 3, h = bh & 7;
  const int lane = threadIdx.x, lo = lane & 15, hi = lane >> 4;
  const size_t qrow0 = (size_t)bh * LSEQ + qt * 16;

  // hoist Q fragments (A-layout: row=lo, k=hi*8+j)
  s16x8 qf[6];
  {
    const ushort_t* qbase = Qt + (qrow0 + lo) * DDIM + hi * 8;
#pragma unroll
    for (int ks = 0; ks < 6; ++ks) qf[ks] = *(const s16x8*)(qbase + ks * 32);
  }

  const f32x4 zero4 = {0.f, 0.f, 0.f, 0.f};
  f32x4 o[4];
  float mrun[4], lrun[4];
#pragma unroll
  for (int j = 0; j < 4; ++j) o[j] = zero4;
#pragma unroll
  for (int r = 0; r < 4; ++r) { mrun[r] = -3.0e38f; lrun[r] = 0.f; }

  const ushort_t* kbase = Kt + ((size_t)bh * LSEQ + lo) * DDIM + hi * 8;
  const ushort_t* vbase = Vt + ((size_t)bh * 64 + lo) * 512 + hi * 8;

  for (int kt = 0; kt < 8; ++kt) {
    f32x4 s[4];
#pragma unroll
    for (int f = 0; f < 4; ++f) s[f] = zero4;

    // ---- S = Q̃·K̃^T : 24 mfma, B-frags straight from L2 ----
    const ushort_t* kb_t = kbase + (size_t)kt * 64 * DDIM;
#pragma unroll
    for (int ks = 0; ks < 6; ++ks)
#pragma unroll
      for (int f = 0; f < 4; ++f) {
        s16x8 kb = *(const s16x8*)(kb_t + (size_t)f * 16 * DDIM + ks * 32);
        s[f] = MFMA16(qf[ks], kb, s[f]);
      }

    // ---- mask ----
#pragma unroll
    for (int f = 0; f < 4; ++f)
      if (mask[b * LSEQ + kt * 64 + f * 16 + lo] == 0) {
        s[f][0] = -3.0e38f; s[f][1] = -3.0e38f; s[f][2] = -3.0e38f; s[f][3] = -3.0e38f;
      }

    // ---- online softmax (rows = hi*4 + r, cols spread over lo & f) ----
#pragma unroll
    for (int r = 0; r < 4; ++r) {
      float tm = fmaxf(fmaxf(s[0][r], s[1][r]), fmaxf(s[2][r], s[3][r]));
      tm = fmaxf(tm, __shfl_xor(tm, 1));
      tm = fmaxf(tm, __shfl_xor(tm, 2));
      tm = fmaxf(tm, __shfl_xor(tm, 4));
      tm = fmaxf(tm, __shfl_xor(tm, 8));
      const float mnew = fmaxf(mrun[r], tm);
      const float corr = __expf(mrun[r] - mnew);
      float ts = 0.f;
#pragma unroll
      for (int f = 0; f < 4; ++f) {
        const float p = __expf(s[f][r] - mnew);
        s[f][r] = p;
        ts += p;
      }
      ts += __shfl_xor(ts, 1);
      ts += __shfl_xor(ts, 2);
      ts += __shfl_xor(ts, 4);
      ts += __shfl_xor(ts, 8);
      lrun[r] = lrun[r] * corr + ts;
      mrun[r] = mnew;
      o[0][r] *= corr; o[1][r] *= corr; o[2][r] *= corr; o[3][r] *= corr;
    }

    // ---- P (C-layout) -> LDS -> A-layout frags ----
#pragma unroll
    for (int f = 0; f < 4; ++f)
#pragma unroll
      for (int r = 0; r < 4; ++r)
        P[hi * 4 + r][f * 16 + lo] = f2b(s[f][r]);

    // ---- O += P·V : V-frags straight from L2 (Vt is V^T) ----
#pragma unroll
    for (int kh = 0; kh < 2; ++kh) {
      s16x8 pa = *(const s16x8*)&P[lo][kh * 32 + hi * 8];
#pragma unroll
      for (int j = 0; j < 4; ++j) {
        s16x8 vb = *(const s16x8*)(vbase + (size_t)j * 16 * 512 + kt * 64 + kh * 32);
        o[j] = MFMA16(pa, vb, o[j]);
      }
    }
  }

  // ---- epilogue ----
#pragma unroll
  for (int j = 0; j < 4; ++j)
#pragma unroll
    for (int r = 0; r < 4; ++r)
      out[((size_t)b * LSEQ + qt * 16 + hi * 4 + r) * 512 + h * 64 + j * 16 + lo] =
          o[j][r] / lrun[r];
}

extern "C" void kernel_launch(void* const* d_in, const int* in_sizes, int n_in,
                              void* d_out, int out_size, void* d_ws, size_t ws_size,
                              hipStream_t stream) {
  const float* x    = (const float*)d_in[0];
  const int*   mask = (const int*)d_in[1];
  const float* W    = (const float*)d_in[2];
  const float* rr   = (const float*)d_in[3];
  const float* rw   = (const float*)d_in[4];
  float* out = (float*)d_out;

  // workspace (bytes): xb 4M | Wt 1.5M | Qt 12.6M | Kt 12.6M | Vt 4M  (~35 MB)
  char* ws = (char*)d_ws;
  ushort_t* xb = (ushort_t*)(ws);
  ushort_t* Wt = (ushort_t*)(ws + 4194304);
  ushort_t* Qt = (ushort_t*)(ws + 5767168);
  ushort_t* Kt = (ushort_t*)(ws + 18350080);
  ushort_t* Vt = (ushort_t*)(ws + 30932992);

  cast_x<<<1024, 256, 0, stream>>>(x, xb);
  cast_transpose_w<<<dim3(16, 48), 256, 0, stream>>>(W, Wt);
  qkv_gemm<<<1536, 64, 0, stream>>>(xb, Wt, rr, Qt, Kt, Vt);
  build_feats<<<4096, 256, 0, stream>>>(Qt, Kt, rr, rw);
  attn_kernel<<<2048, 64, 0, stream>>>(Qt, Kt, Vt, mask, out);
}

// Round 3
// 80.444 us; speedup vs baseline: 3.6510x; 1.4866x over previous
//
#include <hip/hip_runtime.h>
#include <math.h>

#define LSEQ 512
#define DDIM 192

typedef __attribute__((ext_vector_type(8))) short s16x8;
typedef __attribute__((ext_vector_type(4))) float f32x4;
typedef unsigned short ushort_t;
typedef unsigned int uint_t;

#define MFMA16(a, b, c) __builtin_amdgcn_mfma_f32_16x16x32_bf16(a, b, c, 0, 0, 0)

__device__ __forceinline__ ushort_t f2b(float f) {
  union { float f; uint_t u; } v; v.f = f;
  uint_t r = (v.u + 0x7FFFu + ((v.u >> 16) & 1u)) >> 16;
  return (ushort_t)r;
}
__device__ __forceinline__ float b2f(ushort_t u) {
  union { uint_t u; float f; } v; v.u = ((uint_t)u) << 16;
  return v.f;
}

typedef const __attribute__((address_space(1))) void g_void_t;
typedef __attribute__((address_space(3))) void lds_void_t;
__device__ __forceinline__ void load_lds16(const void* g, void* l) {
  __builtin_amdgcn_global_load_lds((g_void_t*)g, (lds_void_t*)l, 16, 0, 0);
}

// swizzled K̃ element index (ushort units): 16B-block XOR with row&7
__device__ __forceinline__ size_t kswz(size_t row, int d) {
  return row * DDIM + (size_t)(((((d >> 3) ^ ((int)row & 7))) << 3) | (d & 7));
}

// ---------------- cast x -> bf16 ----------------
__global__ void cast_x(const float* __restrict__ x, ushort_t* __restrict__ xb) {
  const int i = (blockIdx.x * 256 + threadIdx.x) * 8;
  float4 a = *(const float4*)(x + i);
  float4 b = *(const float4*)(x + i + 4);
  uint4 o;
  o.x = (uint_t)f2b(a.x) | ((uint_t)f2b(a.y) << 16);
  o.y = (uint_t)f2b(a.z) | ((uint_t)f2b(a.w) << 16);
  o.z = (uint_t)f2b(b.x) | ((uint_t)f2b(b.y) << 16);
  o.w = (uint_t)f2b(b.z) | ((uint_t)f2b(b.w) << 16);
  *(uint4*)(xb + i) = o;
}

// ---------------- cast+transpose W: Wt[n][k] = bf16(W[k][n]) ----------------
__global__ void cast_transpose_w(const float* __restrict__ W, ushort_t* __restrict__ Wt) {
  __shared__ float tile[32][33];
  const int tx = threadIdx.x & 31, ty = threadIdx.x >> 5;
  const int k0 = blockIdx.x * 32, n0 = blockIdx.y * 32;
#pragma unroll
  for (int i = 0; i < 4; ++i)
    tile[ty + i * 8][tx] = W[(size_t)(k0 + ty + i * 8) * 1536 + n0 + tx];
  __syncthreads();
#pragma unroll
  for (int i = 0; i < 4; ++i)
    Wt[(size_t)(n0 + ty + i * 8) * 512 + k0 + tx] = f2b(tile[tx][ty + i * 8]);
}

// ---------------- QKV GEMM: bf16 MFMA, 64x64 wave tiles, reg ping-pong ----------------
__global__ __launch_bounds__(64, 2) void qkv_gemm(
    const ushort_t* __restrict__ xb, const ushort_t* __restrict__ Wt,
    const float* __restrict__ rr,
    ushort_t* __restrict__ Qt, ushort_t* __restrict__ Kt, ushort_t* __restrict__ Vt) {
  const int id = blockIdx.x;
  const int t = id >> 3;
  const int np = t % 24, mp = (id & 7) + 8 * (t / 24);
  const int m0 = mp * 64, n0 = np * 64;
  const int lane = threadIdx.x, lo = lane & 15, hi = lane >> 4;

  f32x4 acc[4][4];
  const f32x4 zero4 = {0.f, 0.f, 0.f, 0.f};
#pragma unroll
  for (int i = 0; i < 4; ++i)
#pragma unroll
    for (int j = 0; j < 4; ++j) acc[i][j] = zero4;

  const ushort_t* abase = xb + (size_t)(m0 + lo) * 512 + hi * 8;
  const ushort_t* bbase = Wt + (size_t)(n0 + lo) * 512 + hi * 8;

  s16x8 af[4], bf[4];
#pragma unroll
  for (int i = 0; i < 4; ++i) af[i] = *(const s16x8*)(abase + (size_t)i * 16 * 512);
#pragma unroll
  for (int j = 0; j < 4; ++j) bf[j] = *(const s16x8*)(bbase + (size_t)j * 16 * 512);

#pragma unroll
  for (int ks = 0; ks < 16; ++ks) {
    s16x8 an[4], bn[4];
    if (ks < 15) {
#pragma unroll
      for (int i = 0; i < 4; ++i)
        an[i] = *(const s16x8*)(abase + (size_t)i * 16 * 512 + (ks + 1) * 32);
#pragma unroll
      for (int j = 0; j < 4; ++j)
        bn[j] = *(const s16x8*)(bbase + (size_t)j * 16 * 512 + (ks + 1) * 32);
    }
#pragma unroll
    for (int i = 0; i < 4; ++i)
#pragma unroll
      for (int j = 0; j < 4; ++j)
        acc[i][j] = MFMA16(af[i], bf[j], acc[i][j]);
    if (ks < 15) {
#pragma unroll
      for (int i = 0; i < 4; ++i) { af[i] = an[i]; bf[i] = bn[i]; }
    }
  }

  const int sect = n0 >> 9;
  const int h = (n0 >> 6) & 7;

  if (sect == 0) {
    float bias[4];
#pragma unroll
    for (int j = 0; j < 4; ++j) bias[j] = rr[h * 64 + j * 16 + lo];
#pragma unroll
    for (int i = 0; i < 4; ++i)
#pragma unroll
      for (int r = 0; r < 4; ++r) {
        const int m = m0 + i * 16 + hi * 4 + r;
        const size_t row = ((size_t)(m >> 9) * 8 + h) * 512 + (m & 511);
#pragma unroll
        for (int j = 0; j < 4; ++j)
          Qt[row * DDIM + j * 16 + lo] = f2b((acc[i][j][r] + bias[j]) * 0.125f);
      }
  } else if (sect == 1) {
#pragma unroll
    for (int i = 0; i < 4; ++i)
#pragma unroll
      for (int r = 0; r < 4; ++r) {
        const int m = m0 + i * 16 + hi * 4 + r;
        const size_t row = ((size_t)(m >> 9) * 8 + h) * 512 + (m & 511);
        const int sw = m & 7;
#pragma unroll
        for (int j = 0; j < 4; ++j)
          Kt[row * DDIM + ((((j * 2 + (lo >> 3)) ^ sw) << 3) | (lo & 7))] =
              f2b(acc[i][j][r]);
      }
  } else {
#pragma unroll
    for (int i = 0; i < 4; ++i)
#pragma unroll
      for (int r = 0; r < 4; ++r) {
        const int m = m0 + i * 16 + hi * 4 + r;
        const int b = m >> 9, l = m & 511;
#pragma unroll
        for (int j = 0; j < 4; ++j)
          Vt[(((size_t)b * 8 + h) * 64 + j * 16 + lo) * 512 + l] = f2b(acc[i][j][r]);
      }
  }
}

// ---------------- build augmented features (bf16; K̃ swizzled) ----------------
__global__ void build_feats(ushort_t* __restrict__ Qt, ushort_t* __restrict__ Kt,
                            const float* __restrict__ rr, const float* __restrict__ rw) {
  const int idx = blockIdx.x * blockDim.x + threadIdx.x;
  const int hf = idx & 31;
  const size_t row = (size_t)(idx >> 5);
  const int l = (int)(row & 511);
  const int hh = (int)((row >> 9) & 7);

  const float f = __expf(-(float)hf * 0.29710775393472f);  // ln(10000)/31
  const float a0 = (float)l * f;
  const float a1 = (float)(l + 1) * f;
  float s0, c0, s1, c1;
  __sincosf(a0, &s0, &c0);
  __sincosf(a1, &s1, &c1);

  const size_t qb = row * DDIM;
  const float qr_s = b2f(Qt[qb + hf]);
  const float qr_c = b2f(Qt[qb + 32 + hf]);
  const float qw_s = qr_s + 0.125f * (rw[hh * 64 + hf] - rr[hh * 64 + hf]);
  const float qw_c = qr_c + 0.125f * (rw[hh * 64 + 32 + hf] - rr[hh * 64 + 32 + hf]);
  Qt[qb + 64 + hf]  = f2b(qw_s * c0 + qw_c * s0);
  Qt[qb + 96 + hf]  = f2b(qw_c * c0 - qw_s * s0);
  Qt[qb + 128 + hf] = f2b(0.125f * s1);
  Qt[qb + 160 + hf] = f2b(0.125f * c1);

  const float k_s = b2f(Kt[kswz(row, hf)]);
  const float k_c = b2f(Kt[kswz(row, 32 + hf)]);
  Kt[kswz(row, 64 + hf)]  = f2b(s1);
  Kt[kswz(row, 96 + hf)]  = f2b(c1);
  Kt[kswz(row, 128 + hf)] = f2b(k_s * c0 + k_c * s0);
  Kt[kswz(row, 160 + hf)] = f2b(k_c * c0 - k_s * s0);
}

// ---------------- fused flash attention ----------------
// 256 blocks x 256 thr (4 waves x 32 q-rows). K̃ tiles double-buffered in LDS
// via global_load_lds; V/Q̃ direct from L2. One barrier per k-tile.
__global__ __launch_bounds__(256, 1) void attn_kernel(
    const ushort_t* __restrict__ Qt, const ushort_t* __restrict__ Kt,
    const ushort_t* __restrict__ Vt, const int* __restrict__ mask,
    float* __restrict__ out) {
  __shared__ __align__(16) ushort_t ldsK[2][64 * DDIM];  // 2 x 24 KB
  __shared__ __align__(16) ushort_t P[4][32][72];        // per-wave P transpose

  const int tid = threadIdx.x;
  const int w = tid >> 6;
  const int lane = tid & 63, lo = lane & 15, hi = lane >> 4;
  const int id = blockIdx.x;
  const int bh = (id & 7) + 8 * ((id >> 3) & 7);  // same-head blocks -> same XCD
  const int qg = id >> 6;
  const int b = bh >> 3, h = bh & 7;
  const size_t qrow0 = (size_t)bh * LSEQ + qg * 128 + w * 32;

  // hoist Q̃ fragments (A-layout: row=lo, k=hi*8+j)
  s16x8 qf[2][6];
#pragma unroll
  for (int i = 0; i < 2; ++i)
#pragma unroll
    for (int ks = 0; ks < 6; ++ks)
      qf[i][ks] = *(const s16x8*)(Qt + (qrow0 + i * 16 + lo) * DDIM + ks * 32 + hi * 8);

  const f32x4 zero4 = {0.f, 0.f, 0.f, 0.f};
  f32x4 o[2][4];
  float mrun[2][4], lrun[2][4];
#pragma unroll
  for (int i = 0; i < 2; ++i) {
#pragma unroll
    for (int j = 0; j < 4; ++j) o[i][j] = zero4;
#pragma unroll
    for (int r = 0; r < 4; ++r) { mrun[i][r] = -3.0e38f; lrun[i][r] = 0.f; }
  }

  const char* ksrc = (const char*)(Kt + (size_t)bh * LSEQ * DDIM);
  const ushort_t* vbase = Vt + ((size_t)bh * 64 + lo) * 512 + hi * 8;

  // prologue: stage tile 0 into buf 0
#pragma unroll
  for (int it = 0; it < 6; ++it)
    load_lds16(ksrc + it * 4096 + tid * 16,
               (char*)&ldsK[0][0] + it * 4096 + w * 1024);

  for (int kt = 0; kt < 8; ++kt) {
    const int cur = kt & 1;
    __syncthreads();  // drains vmcnt: tile kt staged; prev-tile reads done

    if (kt < 7) {
      const char* s = ksrc + (kt + 1) * 24576;
      char* d = (char*)&ldsK[cur ^ 1][0] + w * 1024;
#pragma unroll
      for (int it = 0; it < 6; ++it)
        load_lds16(s + it * 4096 + tid * 16, d + it * 4096);
    }

    // ---- S = Q̃·K̃^T from LDS (swizzled) : 48 mfma ----
    f32x4 s[2][4];
#pragma unroll
    for (int i = 0; i < 2; ++i)
#pragma unroll
      for (int f = 0; f < 4; ++f) s[i][f] = zero4;

    const ushort_t* kl = &ldsK[cur][0];
#pragma unroll
    for (int ks = 0; ks < 6; ++ks) {
      s16x8 kb[4];
#pragma unroll
      for (int f = 0; f < 4; ++f) {
        const int r = f * 16 + lo;
        kb[f] = *(const s16x8*)(kl + r * DDIM + (((ks * 4 + hi) ^ (r & 7)) << 3));
      }
#pragma unroll
      for (int f = 0; f < 4; ++f) {
        s[0][f] = MFMA16(qf[0][ks], kb[f], s[0][f]);
        s[1][f] = MFMA16(qf[1][ks], kb[f], s[1][f]);
      }
    }

    // ---- mask ----
#pragma unroll
    for (int f = 0; f < 4; ++f)
      if (mask[b * LSEQ + kt * 64 + f * 16 + lo] == 0) {
#pragma unroll
        for (int i = 0; i < 2; ++i) {
          s[i][f][0] = -3.0e38f; s[i][f][1] = -3.0e38f;
          s[i][f][2] = -3.0e38f; s[i][f][3] = -3.0e38f;
        }
      }

    // ---- online softmax ----
#pragma unroll
    for (int i = 0; i < 2; ++i)
#pragma unroll
      for (int r = 0; r < 4; ++r) {
        float tm = fmaxf(fmaxf(s[i][0][r], s[i][1][r]), fmaxf(s[i][2][r], s[i][3][r]));
        tm = fmaxf(tm, __shfl_xor(tm, 1));
        tm = fmaxf(tm, __shfl_xor(tm, 2));
        tm = fmaxf(tm, __shfl_xor(tm, 4));
        tm = fmaxf(tm, __shfl_xor(tm, 8));
        const float mnew = fmaxf(mrun[i][r], tm);
        const float corr = __expf(mrun[i][r] - mnew);
        float ts = 0.f;
#pragma unroll
        for (int f = 0; f < 4; ++f) {
          const float p = __expf(s[i][f][r] - mnew);
          s[i][f][r] = p;
          ts += p;
        }
        ts += __shfl_xor(ts, 1);
        ts += __shfl_xor(ts, 2);
        ts += __shfl_xor(ts, 4);
        ts += __shfl_xor(ts, 8);
        lrun[i][r] = lrun[i][r] * corr + ts;
        mrun[i][r] = mnew;
        o[i][0][r] *= corr; o[i][1][r] *= corr;
        o[i][2][r] *= corr; o[i][3][r] *= corr;
      }

    // ---- P (C-layout) -> per-wave LDS -> A-layout frags ----
#pragma unroll
    for (int i = 0; i < 2; ++i)
#pragma unroll
      for (int f = 0; f < 4; ++f)
#pragma unroll
        for (int r = 0; r < 4; ++r)
          P[w][i * 16 + hi * 4 + r][f * 16 + lo] = f2b(s[i][f][r]);

    // ---- O += P·V : V-frags straight from L2 ----
#pragma unroll
    for (int kh = 0; kh < 2; ++kh) {
      s16x8 pa0 = *(const s16x8*)&P[w][lo][kh * 32 + hi * 8];
      s16x8 pa1 = *(const s16x8*)&P[w][16 + lo][kh * 32 + hi * 8];
#pragma unroll
      for (int j = 0; j < 4; ++j) {
        s16x8 vb = *(const s16x8*)(vbase + (size_t)j * 16 * 512 + kt * 64 + kh * 32);
        o[0][j] = MFMA16(pa0, vb, o[0][j]);
        o[1][j] = MFMA16(pa1, vb, o[1][j]);
      }
    }
  }

  // ---- epilogue ----
#pragma unroll
  for (int i = 0; i < 2; ++i)
#pragma unroll
    for (int j = 0; j < 4; ++j)
#pragma unroll
      for (int r = 0; r < 4; ++r) {
        const size_t l = qrow0 - (size_t)bh * LSEQ + i * 16 + hi * 4 + r;
        out[((size_t)b * LSEQ + l) * 512 + h * 64 + j * 16 + lo] =
            o[i][j][r] / lrun[i][r];
      }
}

extern "C" void kernel_launch(void* const* d_in, const int* in_sizes, int n_in,
                              void* d_out, int out_size, void* d_ws, size_t ws_size,
                              hipStream_t stream) {
  const float* x    = (const float*)d_in[0];
  const int*   mask = (const int*)d_in[1];
  const float* W    = (const float*)d_in[2];
  const float* rr   = (const float*)d_in[3];
  const float* rw   = (const float*)d_in[4];
  float* out = (float*)d_out;

  char* ws = (char*)d_ws;
  ushort_t* xb = (ushort_t*)(ws);
  ushort_t* Wt = (ushort_t*)(ws + 4194304);
  ushort_t* Qt = (ushort_t*)(ws + 5767168);
  ushort_t* Kt = (ushort_t*)(ws + 18350080);
  ushort_t* Vt = (ushort_t*)(ws + 30932992);

  cast_x<<<1024, 256, 0, stream>>>(x, xb);
  cast_transpose_w<<<dim3(16, 48), 256, 0, stream>>>(W, Wt);
  qkv_gemm<<<1536, 64, 0, stream>>>(xb, Wt, rr, Qt, Kt, Vt);
  build_feats<<<4096, 256, 0, stream>>>(Qt, Kt, rr, rw);
  attn_kernel<<<256, 256, 0, stream>>>(Qt, Kt, Vt, mask, out);
}

// Round 4
// 60.749 us; speedup vs baseline: 4.8346x; 1.3242x over previous
//
#include <hip/hip_runtime.h>
#include <hip/hip_bf16.h>
#include <math.h>

#define LSEQ 512
#define DDIM 192

typedef __attribute__((ext_vector_type(8))) short s16x8;
typedef __attribute__((ext_vector_type(4))) float f32x4;
typedef unsigned short ushort_t;
typedef unsigned int uint_t;

#define MFMA16(a, b, c) __builtin_amdgcn_mfma_f32_16x16x32_bf16(a, b, c, 0, 0, 0)

__device__ __forceinline__ ushort_t f2b(float f) {
  union { float f; uint_t u; } v; v.f = f;
  uint_t r = (v.u + 0x7FFFu + ((v.u >> 16) & 1u)) >> 16;
  return (ushort_t)r;
}
__device__ __forceinline__ float b2f(ushort_t u) {
  union { uint_t u; float f; } v; v.u = ((uint_t)u) << 16;
  return v.f;
}

typedef const __attribute__((address_space(1))) void g_void_t;
typedef __attribute__((address_space(3))) void lds_void_t;
__device__ __forceinline__ void load_lds16(const void* g, void* l) {
  __builtin_amdgcn_global_load_lds((g_void_t*)g, (lds_void_t*)l, 16, 0, 0);
}

// swizzled element index within a row: XOR low-3 bits of 16B-block idx (in-segment)
__device__ __forceinline__ size_t kswz(size_t row, int d) {
  return row * DDIM + (size_t)((d & 0x1C7) | ((((d >> 3) & 7) ^ ((int)row & 7)) << 3));
}

// ---------------- cast x -> bf16, swizzled layout ----------------
__global__ void cast_x(const float* __restrict__ x, ushort_t* __restrict__ xb) {
  const int i = (blockIdx.x * 256 + threadIdx.x) * 8;
  const int row = i >> 9, k = i & 511;
  float4 a = *(const float4*)(x + i);
  float4 b = *(const float4*)(x + i + 4);
  uint4 o;
  o.x = (uint_t)f2b(a.x) | ((uint_t)f2b(a.y) << 16);
  o.y = (uint_t)f2b(a.z) | ((uint_t)f2b(a.w) << 16);
  o.z = (uint_t)f2b(b.x) | ((uint_t)f2b(b.y) << 16);
  o.w = (uint_t)f2b(b.z) | ((uint_t)f2b(b.w) << 16);
  const int dst = row * 512 + (k & 448) + (((((k >> 3) & 7) ^ (row & 7))) << 3);
  *(uint4*)(xb + dst) = o;
}

// ---------------- cast+transpose W: Wt[n][k] = bf16(W[k][n]), swizzled ----------------
__global__ void cast_transpose_w(const float* __restrict__ W, ushort_t* __restrict__ Wt) {
  __shared__ float tile[32][33];
  const int tx = threadIdx.x & 31, ty = threadIdx.x >> 5;
  const int k0 = blockIdx.x * 32, n0 = blockIdx.y * 32;
#pragma unroll
  for (int i = 0; i < 4; ++i)
    tile[ty + i * 8][tx] = W[(size_t)(k0 + ty + i * 8) * 1536 + n0 + tx];
  __syncthreads();
#pragma unroll
  for (int i = 0; i < 4; ++i) {
    const int n = n0 + ty + i * 8, k = k0 + tx;
    Wt[(size_t)n * 512 + (k & 448) + ((((k >> 3) & 7) ^ (n & 7)) << 3) + (k & 7)] =
        f2b(tile[tx][ty + i * 8]);
  }
}

// ---------------- QKV GEMM: 64x128 tile, 4 waves, LDS-staged, BK=64 ----------------
__global__ __launch_bounds__(256, 3) void qkv_gemm(
    const ushort_t* __restrict__ xb, const ushort_t* __restrict__ Wt,
    const float* __restrict__ rr,
    ushort_t* __restrict__ Qt, ushort_t* __restrict__ Kt, ushort_t* __restrict__ Vt) {
  __shared__ __align__(16) ushort_t ldsA[2][64 * 64];
  __shared__ __align__(16) ushort_t ldsB[2][128 * 64];
  const int tid = threadIdx.x;
  const int w = tid >> 6, lane = tid & 63, lo = lane & 15, hi = lane >> 4;
  const int wm = w >> 1, wn = w & 1;
  const int id = blockIdx.x;
  const int mp = id & 63, np = id >> 6;
  const int m0 = mp * 64, n0 = np * 128;

  f32x4 acc[2][4];
  const f32x4 zero4 = {0.f, 0.f, 0.f, 0.f};
#pragma unroll
  for (int i = 0; i < 2; ++i)
#pragma unroll
    for (int j = 0; j < 4; ++j) acc[i][j] = zero4;

  const char* asrc = (const char*)xb + (size_t)m0 * 1024;
  const char* bsrc = (const char*)Wt + (size_t)n0 * 1024;

#define STAGE_QKV(buf, ks)                                                     \
  {                                                                            \
    char* la = (char*)&ldsA[buf][0] + w * 1024;                                \
    char* lb = (char*)&ldsB[buf][0] + w * 1024;                                \
    _Pragma("unroll") for (int it = 0; it < 2; ++it) {                         \
      const int X = it * 4096 + tid * 16;                                      \
      load_lds16(asrc + (size_t)(X >> 7) * 1024 + (ks) * 128 + (X & 127),      \
                 la + it * 4096);                                              \
    }                                                                          \
    _Pragma("unroll") for (int it = 0; it < 4; ++it) {                         \
      const int X = it * 4096 + tid * 16;                                      \
      load_lds16(bsrc + (size_t)(X >> 7) * 1024 + (ks) * 128 + (X & 127),      \
                 lb + it * 4096);                                              \
    }                                                                          \
  }

  STAGE_QKV(0, 0);
  for (int ks = 0; ks < 8; ++ks) {
    const int cur = ks & 1;
    __syncthreads();
    if (ks < 7) STAGE_QKV(cur ^ 1, ks + 1);
    const char* Ab = (const char*)&ldsA[cur][0];
    const char* Bb = (const char*)&ldsB[cur][0];
#pragma unroll
    for (int kh = 0; kh < 2; ++kh) {
      const int sw = ((kh * 4 + hi) ^ (lo & 7)) << 4;
      s16x8 a[2], bf[4];
#pragma unroll
      for (int i = 0; i < 2; ++i)
        a[i] = *(const s16x8*)(Ab + (wm * 32 + i * 16 + lo) * 128 + sw);
#pragma unroll
      for (int j = 0; j < 4; ++j)
        bf[j] = *(const s16x8*)(Bb + (wn * 64 + j * 16 + lo) * 128 + sw);
#pragma unroll
      for (int i = 0; i < 2; ++i)
#pragma unroll
        for (int j = 0; j < 4; ++j)
          acc[i][j] = MFMA16(a[i], bf[j], acc[i][j]);
    }
  }

  const int sect = n0 >> 9;
  const int h = ((n0 + wn * 64) >> 6) & 7;
  const int mrow0 = m0 + wm * 32;

  if (sect == 0) {
    float bias[4];
#pragma unroll
    for (int j = 0; j < 4; ++j) bias[j] = rr[h * 64 + j * 16 + lo];
#pragma unroll
    for (int i = 0; i < 2; ++i)
#pragma unroll
      for (int r = 0; r < 4; ++r) {
        const int m = mrow0 + i * 16 + hi * 4 + r;
        const size_t row = ((size_t)(m >> 9) * 8 + h) * 512 + (m & 511);
#pragma unroll
        for (int j = 0; j < 4; ++j)
          Qt[row * DDIM + j * 16 + lo] = f2b((acc[i][j][r] + bias[j]) * 0.125f);
      }
  } else if (sect == 1) {
#pragma unroll
    for (int i = 0; i < 2; ++i)
#pragma unroll
      for (int r = 0; r < 4; ++r) {
        const int m = mrow0 + i * 16 + hi * 4 + r;
        const size_t row = ((size_t)(m >> 9) * 8 + h) * 512 + (m & 511);
#pragma unroll
        for (int j = 0; j < 4; ++j)
          Kt[row * DDIM + ((((j * 2 + (lo >> 3)) ^ (m & 7)) << 3) | (lo & 7))] =
              f2b(acc[i][j][r]);
      }
  } else {
#pragma unroll
    for (int i = 0; i < 2; ++i) {
      const int b = (mrow0 + i * 16) >> 9;
      const int l0 = (mrow0 + i * 16 + hi * 4) & 511;
#pragma unroll
      for (int j = 0; j < 4; ++j) {
        ushort4 pk;
        pk.x = f2b(acc[i][j][0]); pk.y = f2b(acc[i][j][1]);
        pk.z = f2b(acc[i][j][2]); pk.w = f2b(acc[i][j][3]);
        *(ushort4*)&Vt[(((size_t)b * 8 + h) * 64 + j * 16 + lo) * 512 + l0] = pk;
      }
    }
  }
}

// ---------------- build augmented features (bf16; K̃ swizzled) ----------------
__global__ void build_feats(ushort_t* __restrict__ Qt, ushort_t* __restrict__ Kt,
                            const float* __restrict__ rr, const float* __restrict__ rw) {
  const int idx = blockIdx.x * blockDim.x + threadIdx.x;
  const int hf = idx & 31;
  const size_t row = (size_t)(idx >> 5);
  const int l = (int)(row & 511);
  const int hh = (int)((row >> 9) & 7);

  const float f = __expf(-(float)hf * 0.29710775393472f);  // ln(10000)/31
  float s0, c0, s1, c1;
  __sincosf((float)l * f, &s0, &c0);
  __sincosf((float)(l + 1) * f, &s1, &c1);

  const size_t qb = row * DDIM;
  const float qr_s = b2f(Qt[qb + hf]);
  const float qr_c = b2f(Qt[qb + 32 + hf]);
  const float qw_s = qr_s + 0.125f * (rw[hh * 64 + hf] - rr[hh * 64 + hf]);
  const float qw_c = qr_c + 0.125f * (rw[hh * 64 + 32 + hf] - rr[hh * 64 + 32 + hf]);
  Qt[qb + 64 + hf]  = f2b(qw_s * c0 + qw_c * s0);
  Qt[qb + 96 + hf]  = f2b(qw_c * c0 - qw_s * s0);
  Qt[qb + 128 + hf] = f2b(0.125f * s1);
  Qt[qb + 160 + hf] = f2b(0.125f * c1);

  const float k_s = b2f(Kt[kswz(row, hf)]);
  const float k_c = b2f(Kt[kswz(row, 32 + hf)]);
  Kt[kswz(row, 64 + hf)]  = f2b(s1);
  Kt[kswz(row, 96 + hf)]  = f2b(c1);
  Kt[kswz(row, 128 + hf)] = f2b(k_s * c0 + k_c * s0);
  Kt[kswz(row, 160 + hf)] = f2b(k_c * c0 - k_s * s0);
}

// ---------------- fused flash attention ----------------
// 512 blocks x 256 thr (4 waves x 16 q-rows), 2 blocks/CU. Swapped QK^T:
// each lane owns one q-row -> per-lane softmax (2 shfl). K̃ dbuf in LDS.
__global__ __launch_bounds__(256, 2) void attn_kernel(
    const ushort_t* __restrict__ Qt, const ushort_t* __restrict__ Kt,
    const ushort_t* __restrict__ Vt, const int* __restrict__ mask,
    float* __restrict__ out) {
  __shared__ __align__(16) ushort_t ldsK[2][64 * DDIM];  // 2 x 24 KB
  __shared__ __align__(16) ushort_t P[4][16][72];        // per-wave P [q][k]

  const int tid = threadIdx.x;
  const int w = tid >> 6;
  const int lane = tid & 63, lo = lane & 15, hi = lane >> 4;
  const int id = blockIdx.x;
  const int bh = id & 63, qg = id >> 6;  // same bh -> same XCD (id%8 = bh%8)
  const int b = bh >> 3, h = bh & 7;
  const int q0 = qg * 64 + w * 16;
  const size_t qrow0 = (size_t)bh * LSEQ + q0;

  // Q̃ fragments (B-operand: col=q-row=lo, k=hi*8+j)
  s16x8 qf[6];
#pragma unroll
  for (int ks = 0; ks < 6; ++ks)
    qf[ks] = *(const s16x8*)(Qt + (qrow0 + lo) * DDIM + ks * 32 + hi * 8);

  const f32x4 zero4 = {0.f, 0.f, 0.f, 0.f};
  f32x4 o[4];
#pragma unroll
  for (int j = 0; j < 4; ++j) o[j] = zero4;
  float mrun = -3.0e38f, lrun = 0.f;

  const char* ksrc = (const char*)(Kt + (size_t)bh * LSEQ * DDIM);
  const ushort_t* vbase = Vt + ((size_t)bh * 64 + lo) * 512 + hi * 8;

  // prologue: stage tile 0 into buf 0
  {
    char* d = (char*)&ldsK[0][0] + w * 1024;
#pragma unroll
    for (int it = 0; it < 6; ++it)
      load_lds16(ksrc + it * 4096 + tid * 16, d + it * 4096);
  }

  for (int kt = 0; kt < 8; ++kt) {
    const int cur = kt & 1;
    __syncthreads();
    if (kt < 7) {
      const char* s = ksrc + (kt + 1) * 24576;
      char* d = (char*)&ldsK[cur ^ 1][0] + w * 1024;
#pragma unroll
      for (int it = 0; it < 6; ++it)
        load_lds16(s + it * 4096 + tid * 16, d + it * 4096);
    }

    // ---- S^T = K̃·Q̃^T : 24 mfma; lane owns q-row lo, k = f*16+hi*4+r ----
    f32x4 sf[4];
#pragma unroll
    for (int f = 0; f < 4; ++f) sf[f] = zero4;
    const char* kl = (const char*)&ldsK[cur][0];
    __builtin_amdgcn_s_setprio(1);
#pragma unroll
    for (int ks = 0; ks < 6; ++ks) {
      const int swb = ((ks * 4 + hi) ^ (lo & 7)) << 4;
#pragma unroll
      for (int f = 0; f < 4; ++f) {
        s16x8 ka = *(const s16x8*)(kl + (f * 16 + lo) * 384 + swb);
        sf[f] = MFMA16(ka, qf[ks], sf[f]);
      }
    }
    __builtin_amdgcn_s_setprio(0);

    // ---- mask (ballot-gated; all-ones fast path) ----
    const int mk = mask[b * LSEQ + kt * 64 + lane];
    if (__ballot(mk == 0) != 0ull) {
#pragma unroll
      for (int f = 0; f < 4; ++f)
#pragma unroll
        for (int r = 0; r < 4; ++r)
          if (__shfl(mk, f * 16 + hi * 4 + r) == 0) sf[f][r] = -3.0e38f;
    }

    // ---- per-lane online softmax (16 values, 2 shfl per reduce) ----
    float tm = fmaxf(fmaxf(sf[0][0], sf[0][1]), fmaxf(sf[0][2], sf[0][3]));
#pragma unroll
    for (int f = 1; f < 4; ++f)
      tm = fmaxf(tm, fmaxf(fmaxf(sf[f][0], sf[f][1]), fmaxf(sf[f][2], sf[f][3])));
    tm = fmaxf(tm, __shfl_xor(tm, 16));
    tm = fmaxf(tm, __shfl_xor(tm, 32));

    if (!__all(tm - mrun <= 8.0f)) {  // defer-max (T13)
      const float mnew = fmaxf(mrun, tm);
      const float corr = __expf(mrun - mnew);
      lrun *= corr;
      mrun = mnew;
      float cq[4];
#pragma unroll
      for (int r = 0; r < 4; ++r) cq[r] = __shfl(corr, hi * 4 + r);
#pragma unroll
      for (int j = 0; j < 4; ++j)
#pragma unroll
        for (int r = 0; r < 4; ++r) o[j][r] *= cq[r];
    }

    float ts = 0.f;
#pragma unroll
    for (int f = 0; f < 4; ++f)
#pragma unroll
      for (int r = 0; r < 4; ++r) {
        sf[f][r] = __expf(sf[f][r] - mrun);
        ts += sf[f][r];
      }
    ts += __shfl_xor(ts, 16);
    ts += __shfl_xor(ts, 32);
    lrun += ts;

    // ---- pack P (bf16x4 per f) into per-wave LDS [q=lo][k] ----
#pragma unroll
    for (int f = 0; f < 4; ++f) {
      __hip_bfloat162 p0 = __float22bfloat162_rn(make_float2(sf[f][0], sf[f][1]));
      __hip_bfloat162 p1 = __float22bfloat162_rn(make_float2(sf[f][2], sf[f][3]));
      uint2 u;
      __builtin_memcpy(&u.x, &p0, 4);
      __builtin_memcpy(&u.y, &p1, 4);
      *(uint2*)&P[w][lo][f * 16 + hi * 4] = u;
    }

    // ---- O += P·V : A = P (row=q=lo), B = V^T frags from L2 ----
    __builtin_amdgcn_s_setprio(1);
#pragma unroll
    for (int kh = 0; kh < 2; ++kh) {
      s16x8 pa = *(const s16x8*)&P[w][lo][kh * 32 + hi * 8];
#pragma unroll
      for (int j = 0; j < 4; ++j) {
        s16x8 vb = *(const s16x8*)(vbase + (size_t)j * 16 * 512 + kt * 64 + kh * 32);
        o[j] = MFMA16(pa, vb, o[j]);
      }
    }
    __builtin_amdgcn_s_setprio(0);
  }

  // ---- epilogue: rows q = hi*4+r, lrun lives at lane q ----
  float lq[4];
#pragma unroll
  for (int r = 0; r < 4; ++r) lq[r] = 1.0f / __shfl(lrun, hi * 4 + r);
#pragma unroll
  for (int j = 0; j < 4; ++j)
#pragma unroll
    for (int r = 0; r < 4; ++r)
      out[((size_t)b * LSEQ + q0 + hi * 4 + r) * 512 + h * 64 + j * 16 + lo] =
          o[j][r] * lq[r];
}

extern "C" void kernel_launch(void* const* d_in, const int* in_sizes, int n_in,
                              void* d_out, int out_size, void* d_ws, size_t ws_size,
                              hipStream_t stream) {
  const float* x    = (const float*)d_in[0];
  const int*   mask = (const int*)d_in[1];
  const float* W    = (const float*)d_in[2];
  const float* rr   = (const float*)d_in[3];
  const float* rw   = (const float*)d_in[4];
  float* out = (float*)d_out;

  char* ws = (char*)d_ws;
  ushort_t* xb = (ushort_t*)(ws);
  ushort_t* Wt = (ushort_t*)(ws + 4194304);
  ushort_t* Qt = (ushort_t*)(ws + 5767168);
  ushort_t* Kt = (ushort_t*)(ws + 18350080);
  ushort_t* Vt = (ushort_t*)(ws + 30932992);

  cast_x<<<1024, 256, 0, stream>>>(x, xb);
  cast_transpose_w<<<dim3(16, 48), 256, 0, stream>>>(W, Wt);
  qkv_gemm<<<768, 256, 0, stream>>>(xb, Wt, rr, Qt, Kt, Vt);
  build_feats<<<4096, 256, 0, stream>>>(Qt, Kt, rr, rw);
  attn_kernel<<<512, 256, 0, stream>>>(Qt, Kt, Vt, mask, out);
}